// Round 1
// baseline (87.178 us; speedup 1.0000x reference)
//
#include <hip/hip_runtime.h>
#include <math.h>

// Problem shapes (fixed by setup_inputs)
constexpr int B = 16, T = 1000, P = 64, STR = 6, SCALE = 64;
constexpr int S = T * SCALE;      // 64000 samples per batch row
constexpr int SEGS_PER_BLK = 16;  // segments per block
constexpr int NF = 17;            // frame columns staged (16 segs + 1)
constexpr int NBLK = 63;          // ceil(1001/16)
constexpr int WS_PITCH = 1024;    // per-b pitch of phase-base table in ws
#define NYQ 11025.0f
#define INV_SR (1.0f / 22050.0f)
#define INV_SR_D (1.0 / 22050.0)

__device__ __forceinline__ float fracf_(float x) {
#if __has_builtin(__builtin_amdgcn_fractf)
  return __builtin_amdgcn_fractf(x);
#else
  return x - floorf(x);
#endif
}
__device__ __forceinline__ float sin2pi(float r) {
#if __has_builtin(__builtin_amdgcn_sinf)
  return __builtin_amdgcn_sinf(r);  // v_sin_f32: input in revolutions
#else
  return __sinf(r * 6.28318530717958647692f);
#endif
}
__device__ __forceinline__ float cos2pi(float r) {
#if __has_builtin(__builtin_amdgcn_cosf)
  return __builtin_amdgcn_cosf(r);
#else
  return __cosf(r * 6.28318530717958647692f);
#endif
}

// ---------------------------------------------------------------------------
// Kernel 1: per-batch fp64 prefix scan of f0, emitting the fractional phase
// base of every segment g in [0, 1000]:
//   PS[t] = sum F[0..t]   (inclusive, fp64)
//   baseHz(g) = 32*(PS[g-2] + PS[g-1]),  PS[<0] = 0
//   basef[b][g] = frac(baseHz(g) / SR)   (float)
// One block per b (16 blocks). Replaces the per-block O(T) fp64 redo that
// every one of the 1008 main-kernel blocks used to perform.
// ---------------------------------------------------------------------------
__global__ __launch_bounds__(256) void k_scan(
    const float* __restrict__ six_f0, const int* __restrict__ sidx_p,
    float* __restrict__ basef) {
  const int b = blockIdx.x;
  const int tid = threadIdx.x;
  const int sidx = sidx_p[0] - 1;
  const float* f0row = six_f0 + (size_t)b * T * STR + sidx;  // stride STR

  __shared__ double PSsh[T];  // 8000 B
  __shared__ double wtot[4];

  // 4 consecutive frames per thread, local inclusive sums.
  const int t0 = tid * 4;
  double v0, v1, v2, v3, s;
  {
    float f0 = (t0 + 0 < T) ? f0row[(size_t)(t0 + 0) * STR] : 0.0f;
    float f1 = (t0 + 1 < T) ? f0row[(size_t)(t0 + 1) * STR] : 0.0f;
    float f2 = (t0 + 2 < T) ? f0row[(size_t)(t0 + 2) * STR] : 0.0f;
    float f3 = (t0 + 3 < T) ? f0row[(size_t)(t0 + 3) * STR] : 0.0f;
    v0 = (double)f0;
    v1 = v0 + (double)f1;
    v2 = v1 + (double)f2;
    v3 = v2 + (double)f3;
    s = v3;
  }
  // Wave-inclusive scan of thread sums.
  double wscan = s;
#pragma unroll
  for (int off = 1; off < 64; off <<= 1) {
    double n = __shfl_up(wscan, off, 64);
    if ((tid & 63) >= off) wscan += n;
  }
  if ((tid & 63) == 63) wtot[tid >> 6] = wscan;
  __syncthreads();
  double wbase = 0.0;
  {
    const int w = tid >> 6;
    if (w > 0) wbase += wtot[0];
    if (w > 1) wbase += wtot[1];
    if (w > 2) wbase += wtot[2];
  }
  const double excl = wbase + (wscan - s);  // exclusive prefix before thread
  if (t0 + 0 < T) PSsh[t0 + 0] = excl + v0;
  if (t0 + 1 < T) PSsh[t0 + 1] = excl + v1;
  if (t0 + 2 < T) PSsh[t0 + 2] = excl + v2;
  if (t0 + 3 < T) PSsh[t0 + 3] = excl + v3;
  __syncthreads();

  for (int g = tid; g <= T; g += 256) {
    double ps1 = (g >= 1) ? PSsh[g - 1] : 0.0;
    double ps2 = (g >= 2) ? PSsh[g - 2] : 0.0;
    double phd = 32.0 * (ps1 + ps2) * INV_SR_D;
    phd -= floor(phd);
    basef[(size_t)b * WS_PITCH + g] = (float)phd;
  }
}

// ---------------------------------------------------------------------------
// Kernel 2: fused synth. Block = (b, 16 consecutive segments). No fp64:
// phase base comes straight from basef[b][seg]. A thread owns 4 consecutive
// samples of ONE segment; sin via Chebyshev recurrence over partials.
// ---------------------------------------------------------------------------
__global__ __launch_bounds__(256) void k_fused(
    const float* __restrict__ six_f0, const float* __restrict__ c,
    const float* __restrict__ a, const int* __restrict__ sidx_p,
    const float* __restrict__ basef, float* __restrict__ out) {
  const int b = blockIdx.y;
  const int G0 = blockIdx.x * SEGS_PER_BLK;
  const int fbase = G0 - 1;  // frame of LDS column 0 (clamped at edges)
  const int tid = threadIdx.x;
  const int sidx = sidx_p[0] - 1;
  const float* f0row = six_f0 + (size_t)b * T * STR + sidx;  // stride STR
  const float* cb = c + (size_t)sidx * B * P * T;
  const float* loud = a + (size_t)sidx * B * T + (size_t)b * T;

  __shared__ float Fsh[NF];
  __shared__ float Lsh[NF];
  __shared__ float ampsT[P][NF + 1];  // [partial][frame col], pitch 18

  const int m = tid >> 4;
  const int seg = G0 + m;  // may exceed 1000 (dead lanes)
  // Issue the phase-base load early (L2-resident, 16 lanes broadcast).
  const float base = basef[(size_t)b * WS_PITCH + min(seg, T)];

  // Phase A: stage F and L windows.
  if (tid < NF) {
    int f = min(max(fbase + tid, 0), T - 1);
    Fsh[tid] = f0row[(size_t)f * STR];
  } else if (tid < 2 * NF) {
    int i = tid - NF;
    int f = min(max(fbase + i, 0), T - 1);
    Lsh[i] = loud[f];
  }
  __syncthreads();

  // Phase B: amplitude staging (Nyquist-masked, transposed).
  for (int i = tid; i < P * NF; i += 256) {
    int p = i / NF, fl = i - p * NF;
    int f = min(max(fbase + fl, 0), T - 1);
    float F = Fsh[fl];
    float cv = cb[((size_t)b * P + p) * T + f];
    ampsT[p][fl] = ((float)(p + 1) * F < NYQ) ? cv : 0.0f;
  }
  __syncthreads();

  const int q = tid & 15;
  const int lo_l = m;  // = (seg-1) - fbase, uniform per 16-thread group
  const float Flo = Fsh[lo_l];
  const float Fhi = Fsh[lo_l + 1];
  const float Llo = Lsh[lo_l];
  const float dL = Lsh[lo_l + 1] - Llo;
  const float dF = Fhi - Flo;
  const int kadj = (seg == 0) ? -32 : 0;  // head segment starts mid-window
  const int kp = q * 4;

  float wj[4], twoC[4], scur[4], sprev[4], accj[4];
#pragma unroll
  for (int j = 0; j < 4; ++j) {
    int k = kp + j + kadj;
    float kf1 = (float)(k + 1);
    float local = (kf1 * Flo + dF * kf1 * kf1 * (1.0f / 128.0f)) * INV_SR;
    float phi = fracf_(base + local);
    wj[j] = ((float)k + 0.5f) * (1.0f / 64.0f);
    twoC[j] = 2.0f * cos2pi(phi);
    scur[j] = sin2pi(phi);
    sprev[j] = 0.0f;
    accj[j] = 0.0f;
  }

  const float Fmn = fminf(Flo, Fhi);
  const int pmax = min(P, (int)(NYQ / Fmn) + 1);

  const float* row = &ampsT[0][lo_l];
#pragma unroll 2
  for (int p = 0; p < pmax; ++p) {
    float a0 = row[p * (NF + 1)];
    float a1 = row[p * (NF + 1) + 1];
    float d = a1 - a0;
#pragma unroll
    for (int j = 0; j < 4; ++j) {
      float amp = fmaf(wj[j], d, a0);
      accj[j] = fmaf(amp, scur[j], accj[j]);
      float sn = fmaf(twoC[j], scur[j], -sprev[j]);
      sprev[j] = scur[j];
      scur[j] = sn;
    }
  }

  // live iff all 4 samples in-range: seg 0 -> upper half only, seg 1000 ->
  // lower half only, seg > 1000 -> none.
  bool live = (seg < 1000) ? !(seg == 0 && q < 8) : (seg == 1000 && q < 8);
  if (live) {
    int s0 = seg * 64 - 32 + kp;  // multiple of 4 -> 16B-aligned float4
    float4 r;
    r.x = accj[0] * 0.02f * fmaf(wj[0], dL, Llo);
    r.y = accj[1] * 0.02f * fmaf(wj[1], dL, Llo);
    r.z = accj[2] * 0.02f * fmaf(wj[2], dL, Llo);
    r.w = accj[3] * 0.02f * fmaf(wj[3], dL, Llo);
    *(float4*)(out + (size_t)b * S + s0) = r;
  }
}

extern "C" void kernel_launch(void* const* d_in, const int* in_sizes, int n_in,
                              void* d_out, int out_size, void* d_ws,
                              size_t ws_size, hipStream_t stream) {
  const float* six_f0 = (const float*)d_in[0];
  const float* c = (const float*)d_in[1];
  const float* a = (const float*)d_in[2];
  const int* sidx = (const int*)d_in[3];
  float* out = (float*)d_out;
  float* basef = (float*)d_ws;  // 16 * 1024 * 4 B = 64 KB of workspace

  hipLaunchKernelGGL(k_scan, dim3(B), dim3(256), 0, stream, six_f0, sidx,
                     basef);
  hipLaunchKernelGGL(k_fused, dim3(NBLK, B), dim3(256), 0, stream, six_f0, c,
                     a, sidx, basef, out);
}